// Round 1
// baseline (224.312 us; speedup 1.0000x reference)
//
#include <hip/hip_runtime.h>
#include <cmath>

#define IMG_H 4096
#define IMG_W 4096
#define TX 64
#define TY 64
#define HALO 5
#define IN_W (TX + 2*HALO)   /* 74 */
#define IN_H (TY + 2*HALO)   /* 74 */
#define S_STRIDE (IN_W + 2)  /* 76 */
#define SH_STRIDE (TX + 2)   /* 66 */

struct GW { float w[11]; };

__global__ __launch_bounds__(256) void ssim_tile_kernel(
    const float* __restrict__ img1, const float* __restrict__ img2,
    float* __restrict__ partial, GW gw) {
  __shared__ float s1[IN_H][S_STRIDE];
  __shared__ float s2[IN_H][S_STRIDE];
  __shared__ float sh[IN_H][SH_STRIDE];

  const int tid  = threadIdx.x;
  const int col0 = blockIdx.x * TX;
  const int row0 = blockIdx.y * TY;

  // ---- stage raw tiles with replicate-edge halo ----
  for (int idx = tid; idx < IN_H * IN_W; idx += 256) {
    int r = idx / IN_W, c = idx - r * IN_W;
    int gr = row0 - HALO + r; gr = gr < 0 ? 0 : (gr > IMG_H - 1 ? IMG_H - 1 : gr);
    int gc = col0 - HALO + c; gc = gc < 0 ? 0 : (gc > IMG_W - 1 ? IMG_W - 1 : gc);
    long off = (long)gr * IMG_W + gc;
    s1[r][c] = img1[off];
    s2[r][c] = img2[off];
  }
  __syncthreads();

  const int cv  = tid & 63;          // vertical-pass column owned by this thread
  const int r0v = (tid >> 6) << 4;   // vertical-pass first output row (16-row strip)

  float res[5][16];

  #pragma unroll
  for (int ch = 0; ch < 5; ++ch) {
    // ---- horizontal pass: 74 rows x 8 groups of 8 output cols ----
    for (int idx = tid; idx < IN_H * 8; idx += 256) {
      int r  = idx >> 3;
      int c0 = (idx & 7) * 8;
      float acc[8];
      #pragma unroll
      for (int i = 0; i < 8; ++i) acc[i] = 0.f;
      #pragma unroll
      for (int k = 0; k < 18; ++k) {
        float a = s1[r][c0 + k];
        float b = s2[r][c0 + k];
        float v = (ch == 0) ? a : (ch == 1) ? b : (ch == 2) ? a * a
                : (ch == 3) ? b * b : a * b;
        #pragma unroll
        for (int i = 0; i < 8; ++i) {
          int kk = k - i;
          if (kk >= 0 && kk < 11) acc[i] = fmaf(gw.w[kk], v, acc[i]);
        }
      }
      #pragma unroll
      for (int i = 0; i < 8; ++i) sh[r][c0 + i] = acc[i];
    }
    __syncthreads();

    // ---- vertical pass: each thread owns a 16-row column strip ----
    {
      float acc[16];
      #pragma unroll
      for (int i = 0; i < 16; ++i) acc[i] = 0.f;
      #pragma unroll
      for (int k = 0; k < 26; ++k) {
        float v = sh[r0v + k][cv];
        #pragma unroll
        for (int i = 0; i < 16; ++i) {
          int kk = k - i;
          if (kk >= 0 && kk < 11) acc[i] = fmaf(gw.w[kk], v, acc[i]);
        }
      }
      #pragma unroll
      for (int i = 0; i < 16; ++i) res[ch][i] = acc[i];
    }
    __syncthreads();  // sh reused next channel
  }

  // ---- SSIM map + per-thread sum ----
  const float C1 = 6.5025f, C2 = 58.5225f;
  float sum = 0.f;
  #pragma unroll
  for (int i = 0; i < 16; ++i) {
    float mu1 = res[0][i], mu2 = res[1][i];
    float x2  = res[2][i], y2  = res[3][i], xy = res[4][i];
    float mu1s = mu1 * mu1, mu2s = mu2 * mu2, m12 = mu1 * mu2;
    float sg1 = x2 - mu1s, sg2 = y2 - mu2s, sg12 = xy - m12;
    float num = (2.f * m12 + C1) * (2.f * sg12 + C2);
    float den = (mu1s + mu2s + C1) * (sg1 + sg2 + C2);
    sum += num / den;
  }

  // ---- block reduction (wave shuffle + LDS across 4 waves) ----
  #pragma unroll
  for (int off = 32; off > 0; off >>= 1) sum += __shfl_down(sum, off);
  __shared__ float wsum[4];
  int wave = tid >> 6, lane = tid & 63;
  if (lane == 0) wsum[wave] = sum;
  __syncthreads();
  if (tid == 0)
    partial[blockIdx.y * (IMG_W / TX) + blockIdx.x] =
        wsum[0] + wsum[1] + wsum[2] + wsum[3];
}

__global__ __launch_bounds__(256) void ssim_reduce_kernel(
    const float* __restrict__ partial, float* __restrict__ out) {
  const int NBLK = (IMG_H / TY) * (IMG_W / TX);  // 4096
  int tid = threadIdx.x;
  double s = 0.0;
  for (int i = tid; i < NBLK; i += 256) s += (double)partial[i];
  #pragma unroll
  for (int off = 32; off > 0; off >>= 1) s += __shfl_down(s, off);
  __shared__ double ws[4];
  if ((tid & 63) == 0) ws[tid >> 6] = s;
  __syncthreads();
  if (tid == 0)
    out[0] = (float)((ws[0] + ws[1] + ws[2] + ws[3]) /
                     ((double)IMG_H * (double)IMG_W));
}

extern "C" void kernel_launch(void* const* d_in, const int* in_sizes, int n_in,
                              void* d_out, int out_size, void* d_ws, size_t ws_size,
                              hipStream_t stream) {
  const float* img1 = (const float*)d_in[0];
  const float* img2 = (const float*)d_in[1];
  float* partial = (float*)d_ws;
  float* out = (float*)d_out;

  // exact Gaussian window (size 11, sigma 1.5), normalized in double
  GW gw;
  double g[11], s = 0.0;
  for (int i = 0; i < 11; ++i) {
    double x = i - 5.0;
    g[i] = exp(-(x * x) / (2.0 * 1.5 * 1.5));
    s += g[i];
  }
  for (int i = 0; i < 11; ++i) gw.w[i] = (float)(g[i] / s);

  dim3 grid(IMG_W / TX, IMG_H / TY);
  ssim_tile_kernel<<<grid, 256, 0, stream>>>(img1, img2, partial, gw);
  ssim_reduce_kernel<<<1, 256, 0, stream>>>(partial, out);
}